// Round 3
// baseline (25.865 us; speedup 1.0000x reference)
//
#include <hip/hip_runtime.h>
#include <math.h>

// ESPRIT DOA: only frames 120..123, bins 13..31, 4 mics are consumed by the
// reference. Single workgroup, single barrier, all-float latency pipeline.
// x is (T, 4) row-major float -> one sample (4 mics) == one float4.

#define KLO    13
#define NK     19        // bins 13..31  (400 <= f < 1000, f = k*31.25)
#define NTT    4         // frames 120..123
#define NMIC   4
#define XBASE  30464     // T_START*HOP - NFFT/2
#define PI_F   3.14159265358979f

struct cf { float x, y; };
__device__ inline cf cadd(cf a, cf b){ return {a.x+b.x, a.y+b.y}; }
__device__ inline cf csub(cf a, cf b){ return {a.x-b.x, a.y-b.y}; }
__device__ inline cf cmul(cf a, cf b){ return {a.x*b.x - a.y*b.y, a.x*b.y + a.y*b.x}; }
__device__ inline cf cmulc(cf a, cf b){ return {a.x*b.x + a.y*b.y, a.y*b.x - a.x*b.y}; } // a*conj(b)
__device__ inline cf cscale(cf a, float s){ return {a.x*s, a.y*s}; }
__device__ inline cf csqrtf_c(cf z){
    float r = sqrtf(z.x*z.x + z.y*z.y);
    float u = sqrtf(fmaxf(0.5f*(r + z.x), 0.0f));
    float v = sqrtf(fmaxf(0.5f*(r - z.x), 0.0f));
    if (z.y < 0.0f) v = -v;
    return {u, v};
}

__global__ __launch_bounds__(640)
void esprit_kernel(const float* __restrict__ x, float* __restrict__ out)
{
    __shared__ float XsR[NK][NTT][NMIC], XsI[NK][NTT][NMIC];
    const int tid = threadIdx.x;

    // ---- stage 1: 76 (k,t) bins x 8 sample-parts; direct-global windowed DFT
    if (tid < 608) {
        const int bin = tid >> 3;        // 0..75
        const int p   = tid & 7;         // part: samples [64p, 64p+64)
        const int kk  = bin >> 2;        // 0..18
        const int t   = bin & 3;
        const int k   = KLO + kk;
        const int n0  = p << 6;
        const int j0  = (k * n0) & 511;  // exact k*n0 mod 512

        float cr, ci, wc, ws;
        __sincosf((float)j0 * (-2.0f * PI_F / 512.0f), &ci, &cr);  // e^{-2pi i j0/512}
        __sincosf((float)k  * (-2.0f * PI_F / 512.0f), &ws, &wc);  // step e^{-2pi i k/512}

        const float4* __restrict__ xp = (const float4*)x + (XBASE + t * 256 + n0);

        float re0=0,re1=0,re2=0,re3=0, im0=0,im1=0,im2=0,im3=0;
        #pragma unroll 8
        for (int i = 0; i < 64; ++i) {
            float4 v = xp[i];
            float w = __sinf((float)(n0 + i) * (PI_F / 512.0f));   // sqrt-hann
            float wcr = w * cr, wci = w * ci;
            re0 = fmaf(v.x, wcr, re0); im0 = fmaf(v.x, wci, im0);
            re1 = fmaf(v.y, wcr, re1); im1 = fmaf(v.y, wci, im1);
            re2 = fmaf(v.z, wcr, re2); im2 = fmaf(v.z, wci, im2);
            re3 = fmaf(v.w, wcr, re3); im3 = fmaf(v.w, wci, im3);
            float nr = fmaf(cr, wc, -(ci * ws));
            float ni = fmaf(cr, ws,  (ci * wc));
            cr = nr; ci = ni;
        }
        // reduce the 8 parts (contiguous lanes)
        #pragma unroll
        for (int mask = 1; mask < 8; mask <<= 1) {
            re0 += __shfl_xor(re0, mask); im0 += __shfl_xor(im0, mask);
            re1 += __shfl_xor(re1, mask); im1 += __shfl_xor(im1, mask);
            re2 += __shfl_xor(re2, mask); im2 += __shfl_xor(im2, mask);
            re3 += __shfl_xor(re3, mask); im3 += __shfl_xor(im3, mask);
        }
        if (p == 0) {
            XsR[kk][t][0] = re0; XsI[kk][t][0] = im0;
            XsR[kk][t][1] = re1; XsI[kk][t][1] = im1;
            XsR[kk][t][2] = re2; XsI[kk][t][2] = im2;
            XsR[kk][t][3] = re3; XsI[kk][t][3] = im3;
        }
    }
    __syncthreads();

    // ---- stage 2: per-frequency ESPRIT on wave 0, then in-wave mean -------
    float asum = 0.0f;
    if (tid < 64) {
        if (tid < NK) {
            cf Xm[NMIC][NTT];
            for (int m = 0; m < NMIC; ++m)
                for (int t = 0; t < NTT; ++t)
                    Xm[m][t] = { XsR[tid][t][m], XsI[tid][t][m] };

            // R = (1/4) Xs Xs^H
            cf R[4][4];
            for (int i = 0; i < 4; ++i)
                for (int j = 0; j < 4; ++j) {
                    cf acc = {0.f, 0.f};
                    for (int t = 0; t < 4; ++t) acc = cadd(acc, cmulc(Xm[i][t], Xm[j][t]));
                    R[i][j] = cscale(acc, 0.25f);
                }

            // orthogonal iteration -> dominant 2-D subspace (phi eigvals are
            // similarity-invariant under basis change of the subspace)
            cf Q[4][2];
            for (int i = 0; i < 4; ++i) { Q[i][0] = {0,0}; Q[i][1] = {0,0}; }
            Q[0][0].x = 1.0f; Q[1][1].x = 1.0f;
            #pragma unroll
            for (int it = 0; it < 2; ++it) {
                cf Y[4][2];
                for (int i = 0; i < 4; ++i)
                    for (int c = 0; c < 2; ++c) {
                        cf acc = {0.f, 0.f};
                        for (int j = 0; j < 4; ++j) acc = cadd(acc, cmul(R[i][j], Q[j][c]));
                        Y[i][c] = acc;
                    }
                float n0 = 0.f;
                for (int i = 0; i < 4; ++i) n0 += Y[i][0].x*Y[i][0].x + Y[i][0].y*Y[i][0].y;
                float in0 = 1.0f / sqrtf(n0);
                for (int i = 0; i < 4; ++i) Q[i][0] = cscale(Y[i][0], in0);
                cf pr = {0.f, 0.f};
                for (int i = 0; i < 4; ++i) pr = cadd(pr, cmulc(Y[i][1], Q[i][0])); // Q0^H Y1
                for (int i = 0; i < 4; ++i) Q[i][1] = csub(Y[i][1], cmul(pr, Q[i][0]));
                float n1 = 0.f;
                for (int i = 0; i < 4; ++i) n1 += Q[i][1].x*Q[i][1].x + Q[i][1].y*Q[i][1].y;
                float in1 = 1.0f / sqrtf(n1);
                for (int i = 0; i < 4; ++i) Q[i][1] = cscale(Q[i][1], in1);
            }

            // A = s0^H s0 (Hermitian), B = s0^H s1 ; s0 = rows 0..2, s1 = rows 1..3
            float a00 = 0.f, a11 = 0.f;
            cf a01 = {0.f, 0.f};
            cf B[2][2] = { { {0,0}, {0,0} }, { {0,0}, {0,0} } };
            for (int i = 0; i < 3; ++i) {
                a00 += Q[i][0].x*Q[i][0].x + Q[i][0].y*Q[i][0].y;
                a11 += Q[i][1].x*Q[i][1].x + Q[i][1].y*Q[i][1].y;
                a01 = cadd(a01, cmulc(Q[i][1], Q[i][0]));      // conj(Q0)*Q1
                for (int r2 = 0; r2 < 2; ++r2)
                    for (int c2 = 0; c2 < 2; ++c2)
                        B[r2][c2] = cadd(B[r2][c2], cmulc(Q[i+1][c2], Q[i][r2]));
            }
            float detA = a00*a11 - (a01.x*a01.x + a01.y*a01.y);
            float inv  = 1.0f / detA;
            cf na01  = { -a01.x, -a01.y };
            cf na01c = { -a01.x,  a01.y };
            cf phi00 = cscale(cadd(cscale(B[0][0], a11), cmul(na01,  B[1][0])), inv);
            cf phi01 = cscale(cadd(cscale(B[0][1], a11), cmul(na01,  B[1][1])), inv);
            cf phi10 = cscale(cadd(cmul(na01c, B[0][0]), cscale(B[1][0], a00)), inv);
            cf phi11 = cscale(cadd(cmul(na01c, B[0][1]), cscale(B[1][1], a00)), inv);

            cf tr = cadd(phi00, phi11);
            cf dt = csub(cmul(phi00, phi11), cmul(phi01, phi10));
            cf d2 = csub(cmul(tr, tr), cscale(dt, 4.0f));
            cf disc = csqrtf_c(d2);
            cf lam0 = cscale(cadd(tr, disc), 0.5f);
            cf lam1 = cscale(csub(tr, disc), 0.5f);

            float f     = 31.25f * (float)(KLO + tid);
            float scale = 343.0f / (2.0f * PI_F * f * 0.08f);
            float ph0 = atan2f(lam0.y, lam0.x);
            float ph1 = atan2f(lam1.y, lam1.x);
            float g0 = fminf(fmaxf(ph0 * scale, -1.0f), 1.0f);
            float g1 = fminf(fmaxf(ph1 * scale, -1.0f), 1.0f);
            asum = (asinf(g0) + asinf(g1)) * (180.0f / PI_F);
        }
        // in-wave mean over the 19 bins (lanes >= 19 contribute 0)
        #pragma unroll
        for (int mask = 32; mask >= 1; mask >>= 1)
            asum += __shfl_xor(asum, mask);
        if (tid == 0) out[0] = asum * (1.0f / 38.0f);
    }
}

extern "C" void kernel_launch(void* const* d_in, const int* in_sizes, int n_in,
                              void* d_out, int out_size, void* d_ws, size_t ws_size,
                              hipStream_t stream)
{
    const float* x = (const float*)d_in[0];
    float* out = (float*)d_out;
    esprit_kernel<<<1, 640, 0, stream>>>(x, out);
}

// Round 4
// 12.843 us; speedup vs baseline: 2.0139x; 2.0139x over previous
//
#include <hip/hip_runtime.h>
#include <math.h>

// ESPRIT DOA: only frames 120..123, bins 13..31, 4 mics are consumed by the
// reference. Single workgroup, two barriers, all-float latency pipeline.
// x is (T, 4) row-major float -> one sample (4 mics) == one float4.

#define NFFT   512
#define KLO    13
#define NK     19        // bins 13..31  (400 <= f < 1000, f = k*31.25)
#define NTT    4         // frames 120..123
#define NMIC   4
#define XBASE  30464     // T_START*HOP - NFFT/2
#define PI_F   3.14159265358979f

// xw LDS layout (pre-windowed frames, float, mic-interleaved, skewed):
//   phys(t,n) = t*2084 + (n>>6)*260 + (n&63)*4      (dword units, 16B-aligned)
// frame stride 2084 and chunk stride 260 are ≡4 (mod 32) so per-lane
// ds_read_b128 bank-groups spread instead of stacking.
#define FRM_STRIDE 2084
#define CHK_STRIDE 260
#define XW_SIZE    8328

struct cf { float x, y; };
__device__ inline cf cadd(cf a, cf b){ return {a.x+b.x, a.y+b.y}; }
__device__ inline cf csub(cf a, cf b){ return {a.x-b.x, a.y-b.y}; }
__device__ inline cf cmul(cf a, cf b){ return {a.x*b.x - a.y*b.y, a.x*b.y + a.y*b.x}; }
__device__ inline cf cmulc(cf a, cf b){ return {a.x*b.x + a.y*b.y, a.y*b.x - a.x*b.y}; } // a*conj(b)
__device__ inline cf cscale(cf a, float s){ return {a.x*s, a.y*s}; }
__device__ inline cf csqrtf_c(cf z){
    float r = sqrtf(z.x*z.x + z.y*z.y);
    float u = sqrtf(fmaxf(0.5f*(r + z.x), 0.0f));
    float v = sqrtf(fmaxf(0.5f*(r - z.x), 0.0f));
    if (z.y < 0.0f) v = -v;
    return {u, v};
}

__global__ __launch_bounds__(640)
void esprit_kernel(const float* __restrict__ x, float* __restrict__ out)
{
    __shared__ __align__(16) float xw[XW_SIZE];
    __shared__ float XsR[NK][NTT][NMIC], XsI[NK][NTT][NMIC];

    const int tid = threadIdx.x;

    // ---- stage 0: coalesced float4 staging + window, into skewed LDS ------
    // xw(t,n) = sin(pi*n/512) * x[XBASE + t*256 + n][:]   (2048 float4 total)
    for (int e = tid; e < NTT * NFFT; e += 640) {
        int t = e >> 9;
        int n = e & 511;
        float4 v = ((const float4*)x)[XBASE + t * 256 + n];
        float w = __sinf((float)n * (PI_F / 512.0f));      // sqrt-hann
        v.x *= w; v.y *= w; v.z *= w; v.w *= w;
        *(float4*)&xw[t * FRM_STRIDE + (n >> 6) * CHK_STRIDE + (n & 63) * 4] = v;
    }
    __syncthreads();

    // ---- stage 1: 76 (k,t) bins x 8 sample-parts, rotation recurrence -----
    if (tid < 608) {
        const int bin = tid >> 3;        // 0..75
        const int p   = tid & 7;         // part: samples [64p, 64p+64)
        const int kk  = bin >> 2;        // 0..18
        const int t   = bin & 3;
        const int k   = KLO + kk;
        const int n0  = p << 6;
        const int j0  = (k * n0) & 511;  // exact k*n0 mod 512

        float cr, ci, wc, ws;
        __sincosf((float)j0 * (-2.0f * PI_F / 512.0f), &ci, &cr);  // e^{-2pi i j0/512}
        __sincosf((float)k  * (-2.0f * PI_F / 512.0f), &ws, &wc);  // step e^{-2pi i k/512}

        float re0=0,re1=0,re2=0,re3=0, im0=0,im1=0,im2=0,im3=0;
        const int boff = t * FRM_STRIDE + p * CHK_STRIDE;   // 16B-aligned
        #pragma unroll 8
        for (int i = 0; i < 64; ++i) {
            float4 v = *(const float4*)&xw[boff + 4*i];
            re0 = fmaf(v.x, cr, re0); im0 = fmaf(v.x, ci, im0);
            re1 = fmaf(v.y, cr, re1); im1 = fmaf(v.y, ci, im1);
            re2 = fmaf(v.z, cr, re2); im2 = fmaf(v.z, ci, im2);
            re3 = fmaf(v.w, cr, re3); im3 = fmaf(v.w, ci, im3);
            float nr = fmaf(cr, wc, -(ci * ws));
            float ni = fmaf(cr, ws,  (ci * wc));
            cr = nr; ci = ni;
        }
        // reduce the 8 parts (contiguous lanes)
        #pragma unroll
        for (int mask = 1; mask < 8; mask <<= 1) {
            re0 += __shfl_xor(re0, mask); im0 += __shfl_xor(im0, mask);
            re1 += __shfl_xor(re1, mask); im1 += __shfl_xor(im1, mask);
            re2 += __shfl_xor(re2, mask); im2 += __shfl_xor(im2, mask);
            re3 += __shfl_xor(re3, mask); im3 += __shfl_xor(im3, mask);
        }
        if (p == 0) {
            XsR[kk][t][0] = re0; XsI[kk][t][0] = im0;
            XsR[kk][t][1] = re1; XsI[kk][t][1] = im1;
            XsR[kk][t][2] = re2; XsI[kk][t][2] = im2;
            XsR[kk][t][3] = re3; XsI[kk][t][3] = im3;
        }
    }
    __syncthreads();

    // ---- stage 2: per-frequency ESPRIT on wave 0, then in-wave mean -------
    float asum = 0.0f;
    if (tid < 64) {
        if (tid < NK) {
            cf Xm[NMIC][NTT];
            for (int m = 0; m < NMIC; ++m)
                for (int t = 0; t < NTT; ++t)
                    Xm[m][t] = { XsR[tid][t][m], XsI[tid][t][m] };

            // R = (1/4) Xs Xs^H
            cf R[4][4];
            for (int i = 0; i < 4; ++i)
                for (int j = 0; j < 4; ++j) {
                    cf acc = {0.f, 0.f};
                    for (int t = 0; t < 4; ++t) acc = cadd(acc, cmulc(Xm[i][t], Xm[j][t]));
                    R[i][j] = cscale(acc, 0.25f);
                }

            // orthogonal iteration -> dominant 2-D subspace (phi eigvals are
            // similarity-invariant under basis change of the subspace)
            cf Q[4][2];
            for (int i = 0; i < 4; ++i) { Q[i][0] = {0,0}; Q[i][1] = {0,0}; }
            Q[0][0].x = 1.0f; Q[1][1].x = 1.0f;
            #pragma unroll
            for (int it = 0; it < 2; ++it) {
                cf Y[4][2];
                for (int i = 0; i < 4; ++i)
                    for (int c = 0; c < 2; ++c) {
                        cf acc = {0.f, 0.f};
                        for (int j = 0; j < 4; ++j) acc = cadd(acc, cmul(R[i][j], Q[j][c]));
                        Y[i][c] = acc;
                    }
                float n0 = 0.f;
                for (int i = 0; i < 4; ++i) n0 += Y[i][0].x*Y[i][0].x + Y[i][0].y*Y[i][0].y;
                float in0 = 1.0f / sqrtf(n0);
                for (int i = 0; i < 4; ++i) Q[i][0] = cscale(Y[i][0], in0);
                cf pr = {0.f, 0.f};
                for (int i = 0; i < 4; ++i) pr = cadd(pr, cmulc(Y[i][1], Q[i][0])); // Q0^H Y1
                for (int i = 0; i < 4; ++i) Q[i][1] = csub(Y[i][1], cmul(pr, Q[i][0]));
                float n1 = 0.f;
                for (int i = 0; i < 4; ++i) n1 += Q[i][1].x*Q[i][1].x + Q[i][1].y*Q[i][1].y;
                float in1 = 1.0f / sqrtf(n1);
                for (int i = 0; i < 4; ++i) Q[i][1] = cscale(Q[i][1], in1);
            }

            // A = s0^H s0 (Hermitian), B = s0^H s1 ; s0 = rows 0..2, s1 = rows 1..3
            float a00 = 0.f, a11 = 0.f;
            cf a01 = {0.f, 0.f};
            cf B[2][2] = { { {0,0}, {0,0} }, { {0,0}, {0,0} } };
            for (int i = 0; i < 3; ++i) {
                a00 += Q[i][0].x*Q[i][0].x + Q[i][0].y*Q[i][0].y;
                a11 += Q[i][1].x*Q[i][1].x + Q[i][1].y*Q[i][1].y;
                a01 = cadd(a01, cmulc(Q[i][1], Q[i][0]));      // conj(Q0)*Q1
                for (int r2 = 0; r2 < 2; ++r2)
                    for (int c2 = 0; c2 < 2; ++c2)
                        B[r2][c2] = cadd(B[r2][c2], cmulc(Q[i+1][c2], Q[i][r2]));
            }
            float detA = a00*a11 - (a01.x*a01.x + a01.y*a01.y);
            float inv  = 1.0f / detA;
            cf na01  = { -a01.x, -a01.y };
            cf na01c = { -a01.x,  a01.y };
            cf phi00 = cscale(cadd(cscale(B[0][0], a11), cmul(na01,  B[1][0])), inv);
            cf phi01 = cscale(cadd(cscale(B[0][1], a11), cmul(na01,  B[1][1])), inv);
            cf phi10 = cscale(cadd(cmul(na01c, B[0][0]), cscale(B[1][0], a00)), inv);
            cf phi11 = cscale(cadd(cmul(na01c, B[0][1]), cscale(B[1][1], a00)), inv);

            cf tr = cadd(phi00, phi11);
            cf dt = csub(cmul(phi00, phi11), cmul(phi01, phi10));
            cf d2 = csub(cmul(tr, tr), cscale(dt, 4.0f));
            cf disc = csqrtf_c(d2);
            cf lam0 = cscale(cadd(tr, disc), 0.5f);
            cf lam1 = cscale(csub(tr, disc), 0.5f);

            float f     = 31.25f * (float)(KLO + tid);
            float scale = 343.0f / (2.0f * PI_F * f * 0.08f);
            float ph0 = atan2f(lam0.y, lam0.x);
            float ph1 = atan2f(lam1.y, lam1.x);
            float g0 = fminf(fmaxf(ph0 * scale, -1.0f), 1.0f);
            float g1 = fminf(fmaxf(ph1 * scale, -1.0f), 1.0f);
            asum = (asinf(g0) + asinf(g1)) * (180.0f / PI_F);
        }
        // in-wave mean over the 19 bins (lanes >= 19 contribute 0)
        #pragma unroll
        for (int mask = 32; mask >= 1; mask >>= 1)
            asum += __shfl_xor(asum, mask);
        if (tid == 0) out[0] = asum * (1.0f / 38.0f);
    }
}

extern "C" void kernel_launch(void* const* d_in, const int* in_sizes, int n_in,
                              void* d_out, int out_size, void* d_ws, size_t ws_size,
                              hipStream_t stream)
{
    const float* x = (const float*)d_in[0];
    float* out = (float*)d_out;
    esprit_kernel<<<1, 640, 0, stream>>>(x, out);
}